// Round 7
// baseline (438.200 us; speedup 1.0000x reference)
//
#include <hip/hip_runtime.h>

// Problem constants (fixed by the reference file).
#define D_DIM    512
#define B_DIM    64
#define L_DIM    2048
#define NBLK1    256       // phase-1 blocks; 1/CU (132 KiB LDS)
#define THREADS1 512
#define MAXCHUNK 512
#define XSZ      (B_DIM * D_DIM)          // 32768 floats per partial
#define KSPLIT   8                        // reduce k-parallelism

// Native clang vector type.
typedef float f32x4 __attribute__((ext_vector_type(4)));

// ---------------------------------------------------------------------------
// Phase 1: per-block segment-sum into a [B, D] LDS accumulator, plain
// (non-atomic) ds_read/add/ds_write -- thread tid owns column tid exclusively.
// Measured (R5->R6): LDS atomicAdd ~200cyc serialized; plain RMW ~6cyc.
// Positions staged and read as int2 -> ds_read_b64, one fewer LDS op/node.
// Duplicate-position hazard (p.x==p.y, P=1/64): both reads issue before the
// adds; second write adds 2v, write order a-then-b keeps it correct.
// ---------------------------------------------------------------------------
__device__ __forceinline__ void rmw2(float* acc, int ia, int ib, float v) {
    float ra = acc[ia];
    float rb = acc[ib];
    float addb = (ia == ib) ? (v + v) : v;
    acc[ia] = ra + v;      // if ia==ib this write is superseded by the next
    acc[ib] = rb + addb;
}

__global__ __launch_bounds__(THREADS1)
void seg_sum_kernel(const float* __restrict__ g, const int* __restrict__ tp,
                    float* __restrict__ dst, int N, int chunk, int use_atomic) {
    __shared__ float acc[XSZ];             // 128 KiB
    __shared__ int2  pos2[MAXCHUNK];       // 4 KiB, (p0,p1) per node
    const int tid = threadIdx.x;

    for (int i = tid; i < XSZ; i += THREADS1) acc[i] = 0.0f;

    int start = blockIdx.x * chunk;
    int end   = start + chunk; if (end > N) end = N;
    int n     = end - start;
    const int2* tp2 = (const int2*)(tp + 2 * start);   // 8B-aligned (start even*2)
    for (int i = tid; i < n; i += THREADS1) pos2[i] = tp2[i];
    __syncthreads();

    const float* gp = g + (size_t)start * D_DIM + tid;

    int i = 0;
    for (; i + 8 <= n; i += 8) {
        // 8 independent 256 B loads in flight per wave (16 KB/CU at 8 waves).
        float v0 = gp[(size_t)(i + 0) * D_DIM];
        float v1 = gp[(size_t)(i + 1) * D_DIM];
        float v2 = gp[(size_t)(i + 2) * D_DIM];
        float v3 = gp[(size_t)(i + 3) * D_DIM];
        float v4 = gp[(size_t)(i + 4) * D_DIM];
        float v5 = gp[(size_t)(i + 5) * D_DIM];
        float v6 = gp[(size_t)(i + 6) * D_DIM];
        float v7 = gp[(size_t)(i + 7) * D_DIM];
        int2 p0 = pos2[i+0], p1 = pos2[i+1], p2 = pos2[i+2], p3 = pos2[i+3];
        int2 p4 = pos2[i+4], p5 = pos2[i+5], p6 = pos2[i+6], p7 = pos2[i+7];
        rmw2(acc, p0.x * D_DIM + tid, p0.y * D_DIM + tid, v0);
        rmw2(acc, p1.x * D_DIM + tid, p1.y * D_DIM + tid, v1);
        rmw2(acc, p2.x * D_DIM + tid, p2.y * D_DIM + tid, v2);
        rmw2(acc, p3.x * D_DIM + tid, p3.y * D_DIM + tid, v3);
        rmw2(acc, p4.x * D_DIM + tid, p4.y * D_DIM + tid, v4);
        rmw2(acc, p5.x * D_DIM + tid, p5.y * D_DIM + tid, v5);
        rmw2(acc, p6.x * D_DIM + tid, p6.y * D_DIM + tid, v6);
        rmw2(acc, p7.x * D_DIM + tid, p7.y * D_DIM + tid, v7);
    }
    for (; i < n; ++i) {
        float v = gp[(size_t)i * D_DIM];
        int2 p = pos2[i];
        rmw2(acc, p.x * D_DIM + tid, p.y * D_DIM + tid, v);
    }
    __syncthreads();

    if (use_atomic) {
        for (int j = tid; j < XSZ; j += THREADS1) {
            float v = acc[j];
            if (v != 0.0f) atomicAdd(&dst[j], v);
        }
    } else {
        // Plain coalesced float4 stores of this block's partial.
        f32x4* outp = (f32x4*)(dst + (size_t)blockIdx.x * XSZ);
        const f32x4* a4 = (const f32x4*)acc;
        for (int j = tid; j < XSZ / 4; j += THREADS1) outp[j] = a4[j];
    }
}

// ---------------------------------------------------------------------------
// Reduce 256 partials -> KSPLIT partial x vectors (final sum folded into
// bcast). 1024 blocks x 256 thr = 16 waves/CU, 32 KB in flight/CU (R6 had
// only 2 waves/CU here).
// ---------------------------------------------------------------------------
__global__ __launch_bounds__(256)
void reduce_partials(const float* __restrict__ p, float* __restrict__ xp) {
    const int jblks = XSZ / 256;                 // 128
    int jblk = blockIdx.x & (jblks - 1);
    int ks   = blockIdx.x >> 7;                  // 0..KSPLIT-1
    int j    = (jblk << 8) + threadIdx.x;
    const float* pj = p + j + (size_t)ks * (NBLK1 / KSPLIT) * XSZ;
    float s = 0.0f;
    #pragma unroll 8
    for (int k = 0; k < NBLK1 / KSPLIT; ++k) s += pj[(size_t)k * XSZ];
    xp[(size_t)ks * XSZ + j] = s;
}

// ---------------------------------------------------------------------------
// Phase 2: broadcast. PLAIN dwordx4 stores (nontemporal dropped -- the
// harness's own fill kernel hits 6.5 TB/s with plain stores, R6 measured).
// Each wave owns one contiguous 64 KB span; sums nparts xp slices on entry
// (L2-hot, 2*nparts loads).
// ---------------------------------------------------------------------------
#define BC_BLOCKS  1024
#define BC_THREADS 256
__global__ __launch_bounds__(BC_THREADS)
void bcast_lin(const float* __restrict__ xp, int nparts, f32x4* __restrict__ out) {
    int gw   = (blockIdx.x * BC_THREADS + threadIdx.x) >> 6;  // wave 0..4095
    int lane = threadIdx.x & 63;
    size_t base = (size_t)gw * 4096;          // float4 units; span = 64 KB
    int b = (int)(base >> 18);                // 2^18 float4s per b

    const f32x4* x4 = (const f32x4*)xp;
    f32x4 v0 = 0.0f, v1 = 0.0f;
    for (int p = 0; p < nparts; ++p) {
        v0 += x4[(size_t)p * (XSZ / 4) + (b << 7) + lane];
        v1 += x4[(size_t)p * (XSZ / 4) + (b << 7) + 64 + lane];
    }

    f32x4* o = out + base + lane;
    #pragma unroll 8
    for (int t = 0; t < 64; t += 2) {
        o[(size_t)t * 64]      = v0;
        o[(size_t)t * 64 + 64] = v1;
    }
}

extern "C" void kernel_launch(void* const* d_in, const int* in_sizes, int n_in,
                              void* d_out, int out_size, void* d_ws, size_t ws_size,
                              hipStream_t stream) {
    const float* g   = (const float*)d_in[0];
    const int*   tp  = (const int*)d_in[1];
    float*       out = (float*)d_out;

    int N = in_sizes[1] / 2;               // 100000
    int chunk = (N + NBLK1 - 1) / NBLK1;   // 391 <= MAXCHUNK

    const size_t need = (size_t)(NBLK1 + KSPLIT) * XSZ * sizeof(float);  // 34.6 MB

    if (ws_size >= need) {
        float* partials = (float*)d_ws;                    // [256][32768]
        float* xp       = partials + (size_t)NBLK1 * XSZ;  // [KSPLIT][32768]
        seg_sum_kernel<<<NBLK1, THREADS1, 0, stream>>>(g, tp, partials, N, chunk, 0);
        reduce_partials<<<(XSZ / 256) * KSPLIT, 256, 0, stream>>>(partials, xp);
        bcast_lin<<<BC_BLOCKS, BC_THREADS, 0, stream>>>(xp, KSPLIT, (f32x4*)out);
    } else {
        // Fallback: atomic flush into x (d_ws poisoned 0xAA -> zero it first).
        float* x = (float*)d_ws;
        (void)hipMemsetAsync(d_ws, 0, XSZ * sizeof(float), stream);
        seg_sum_kernel<<<NBLK1, THREADS1, 0, stream>>>(g, tp, x, N, chunk, 1);
        bcast_lin<<<BC_BLOCKS, BC_THREADS, 0, stream>>>(x, 1, (f32x4*)out);
    }
}

// Round 8
// 436.302 us; speedup vs baseline: 1.0043x; 1.0043x over previous
//
#include <hip/hip_runtime.h>

// Problem constants (fixed by the reference file).
#define D_DIM    512
#define B_DIM    64
#define L_DIM    2048
#define NBLK1    256       // phase-1 blocks; 1/CU (132 KiB LDS)
#define THREADS1 256       // f2 ownership: thread t owns float2-column t (256 = D/2)
#define MAXCHUNK 512
#define XSZ      (B_DIM * D_DIM)          // 32768 floats per partial
#define KSPLIT   8

typedef float f32x2 __attribute__((ext_vector_type(2)));
typedef float f32x4 __attribute__((ext_vector_type(4)));

// ---------------------------------------------------------------------------
// Phase 1: segment-sum into a [B, D] LDS accumulator with FLOAT2-granular
// exclusive column ownership: 256 threads x 1 f2-col each -> plain (non-
// atomic) ds_read_b64 / v_add / ds_write_b64. Halves LDS wave-ops/node vs
// the b32 version (R6/R7: 32 b32-ops -> 16 b64-ops per node) and halves the
// per-wave read->write stall chains. Races: none -- a thread serially RMWs
// only its own column; in-order LDS per wave makes cross-node same-position
// updates correct; same-node dup position handled in rmw2 (add 2v on the
// second write, order a-then-b).
// Measured history: LDS atomicAdd ~200cyc serialized (R1-R5); plain RMW won
// 857->435 us (R6).
// ---------------------------------------------------------------------------
__device__ __forceinline__ void rmw2(f32x2* acc, int ia, int ib, f32x2 v) {
    f32x2 ra = acc[ia];
    f32x2 rb = acc[ib];
    f32x2 addb = (ia == ib) ? (v + v) : v;
    acc[ia] = ra + v;      // if ia==ib this write is superseded by the next
    acc[ib] = rb + addb;
}

__global__ __launch_bounds__(THREADS1)
void seg_sum_kernel(const float* __restrict__ g, const int* __restrict__ tp,
                    float* __restrict__ dst, int N, int chunk, int use_atomic) {
    __shared__ f32x2 acc[B_DIM * (D_DIM / 2)];   // 128 KiB; acc[b*256 + c2]
    __shared__ int2  pos2[MAXCHUNK];             // 4 KiB
    const int tid = threadIdx.x;                 // owned f2-column

    {   // zero-init via f4 writes
        f32x4* a4 = (f32x4*)acc;
        for (int i = tid; i < XSZ / 4; i += THREADS1) a4[i] = (f32x4)0.0f;
    }

    int start = blockIdx.x * chunk;
    int end   = start + chunk; if (end > N) end = N;
    int n     = end - start;
    const int2* tp2 = (const int2*)(tp + 2 * start);
    for (int i = tid; i < n; i += THREADS1) pos2[i] = tp2[i];
    __syncthreads();

    // g as f2: row i starts at f2-offset i*256; thread reads its own column.
    const f32x2* gp = (const f32x2*)g + (size_t)start * (D_DIM / 2) + tid;

    int i = 0;
    for (; i + 8 <= n; i += 8) {
        // 8 independent dwordx2 loads in flight per wave.
        f32x2 v0 = gp[(size_t)(i + 0) * (D_DIM / 2)];
        f32x2 v1 = gp[(size_t)(i + 1) * (D_DIM / 2)];
        f32x2 v2 = gp[(size_t)(i + 2) * (D_DIM / 2)];
        f32x2 v3 = gp[(size_t)(i + 3) * (D_DIM / 2)];
        f32x2 v4 = gp[(size_t)(i + 4) * (D_DIM / 2)];
        f32x2 v5 = gp[(size_t)(i + 5) * (D_DIM / 2)];
        f32x2 v6 = gp[(size_t)(i + 6) * (D_DIM / 2)];
        f32x2 v7 = gp[(size_t)(i + 7) * (D_DIM / 2)];
        int2 p0 = pos2[i+0], p1 = pos2[i+1], p2 = pos2[i+2], p3 = pos2[i+3];
        int2 p4 = pos2[i+4], p5 = pos2[i+5], p6 = pos2[i+6], p7 = pos2[i+7];
        rmw2(acc, p0.x * (D_DIM/2) + tid, p0.y * (D_DIM/2) + tid, v0);
        rmw2(acc, p1.x * (D_DIM/2) + tid, p1.y * (D_DIM/2) + tid, v1);
        rmw2(acc, p2.x * (D_DIM/2) + tid, p2.y * (D_DIM/2) + tid, v2);
        rmw2(acc, p3.x * (D_DIM/2) + tid, p3.y * (D_DIM/2) + tid, v3);
        rmw2(acc, p4.x * (D_DIM/2) + tid, p4.y * (D_DIM/2) + tid, v4);
        rmw2(acc, p5.x * (D_DIM/2) + tid, p5.y * (D_DIM/2) + tid, v5);
        rmw2(acc, p6.x * (D_DIM/2) + tid, p6.y * (D_DIM/2) + tid, v6);
        rmw2(acc, p7.x * (D_DIM/2) + tid, p7.y * (D_DIM/2) + tid, v7);
    }
    for (; i < n; ++i) {
        f32x2 v = gp[(size_t)i * (D_DIM / 2)];
        int2 p = pos2[i];
        rmw2(acc, p.x * (D_DIM/2) + tid, p.y * (D_DIM/2) + tid, v);
    }
    __syncthreads();

    if (use_atomic) {
        const float* af = (const float*)acc;
        for (int j = tid; j < XSZ; j += THREADS1) {
            float v = af[j];
            if (v != 0.0f) atomicAdd(&dst[j], v);
        }
    } else {
        // Plain coalesced float4 stores of this block's partial.
        f32x4* outp = (f32x4*)(dst + (size_t)blockIdx.x * XSZ);
        const f32x4* a4 = (const f32x4*)acc;
        for (int j = tid; j < XSZ / 4; j += THREADS1) outp[j] = a4[j];
    }
}

// ---------------------------------------------------------------------------
// Reduce 256 partials -> KSPLIT partial x vectors, f4-vectorized.
// 256 blocks x 256 thr; each thread sums 32 dwordx4 loads (strided 32 KB).
// ---------------------------------------------------------------------------
__global__ __launch_bounds__(256)
void reduce_partials(const f32x4* __restrict__ p, f32x4* __restrict__ xp) {
    const int J4 = XSZ / 4;                      // 8192 f4 per partial
    int jblk = blockIdx.x & 31;                  // 32 jblks x 256 thr = 8192
    int ks   = blockIdx.x >> 5;                  // 0..KSPLIT-1
    int j    = (jblk << 8) + threadIdx.x;
    const f32x4* pj = p + j + (size_t)ks * (NBLK1 / KSPLIT) * J4;
    f32x4 s = (f32x4)0.0f;
    #pragma unroll 8
    for (int k = 0; k < NBLK1 / KSPLIT; ++k) s += pj[(size_t)k * J4];
    xp[(size_t)ks * J4 + j] = s;
}

// ---------------------------------------------------------------------------
// Phase 2: broadcast. 4096 blocks x 256 thr = 16384 waves, each streaming one
// contiguous 16 KB span (plain dwordx4 stores -- the harness fill hits
// 6.5 TB/s with this pattern). Sums the KSPLIT xp slices on entry (L2-hot).
// ---------------------------------------------------------------------------
#define BC_BLOCKS  4096
#define BC_THREADS 256
__global__ __launch_bounds__(BC_THREADS)
void bcast_lin(const f32x4* __restrict__ xp, int nparts, f32x4* __restrict__ out) {
    int gw   = (blockIdx.x * BC_THREADS + threadIdx.x) >> 6;  // wave 0..16383
    int lane = threadIdx.x & 63;
    size_t base = (size_t)gw * 1024;          // f4 units; span = 16 KB
    int b = (int)(base >> 18);                // 2^18 f4 per b

    f32x4 v0 = (f32x4)0.0f, v1 = (f32x4)0.0f;
    for (int p = 0; p < nparts; ++p) {
        v0 += xp[(size_t)p * (XSZ / 4) + (b << 7) + lane];
        v1 += xp[(size_t)p * (XSZ / 4) + (b << 7) + 64 + lane];
    }

    f32x4* o = out + base + lane;
    #pragma unroll
    for (int t = 0; t < 16; t += 2) {
        o[(size_t)t * 64]      = v0;
        o[(size_t)t * 64 + 64] = v1;
    }
}

extern "C" void kernel_launch(void* const* d_in, const int* in_sizes, int n_in,
                              void* d_out, int out_size, void* d_ws, size_t ws_size,
                              hipStream_t stream) {
    const float* g   = (const float*)d_in[0];
    const int*   tp  = (const int*)d_in[1];
    f32x4*       out = (f32x4*)d_out;

    int N = in_sizes[1] / 2;               // 100000
    int chunk = (N + NBLK1 - 1) / NBLK1;   // 391 <= MAXCHUNK

    const size_t need = (size_t)(NBLK1 + KSPLIT) * XSZ * sizeof(float);  // 34.6 MB

    if (ws_size >= need) {
        float* partials = (float*)d_ws;                    // [256][32768]
        float* xp       = partials + (size_t)NBLK1 * XSZ;  // [KSPLIT][32768]
        seg_sum_kernel<<<NBLK1, THREADS1, 0, stream>>>(g, tp, partials, N, chunk, 0);
        reduce_partials<<<32 * KSPLIT, 256, 0, stream>>>((const f32x4*)partials,
                                                         (f32x4*)xp);
        bcast_lin<<<BC_BLOCKS, BC_THREADS, 0, stream>>>((const f32x4*)xp, KSPLIT, out);
    } else {
        // Fallback: atomic flush into x (d_ws poisoned 0xAA -> zero it first).
        float* x = (float*)d_ws;
        (void)hipMemsetAsync(d_ws, 0, XSZ * sizeof(float), stream);
        seg_sum_kernel<<<NBLK1, THREADS1, 0, stream>>>(g, tp, x, N, chunk, 1);
        bcast_lin<<<BC_BLOCKS, BC_THREADS, 0, stream>>>((const f32x4*)x, 1, out);
    }
}